// Round 2
// baseline (179.578 us; speedup 1.0000x reference)
//
#include <hip/hip_runtime.h>
#include <hip/hip_bf16.h>
#include <stdint.h>

typedef unsigned short ushort_t;
typedef __attribute__((ext_vector_type(8))) short short8;   // 8 bf16 (4 VGPRs)
typedef __attribute__((ext_vector_type(4))) float f32x4;

#define N_NODES 384
#define HF      512
#define TI      8      // i-rows per attention block

__device__ inline ushort_t f2bf(float f) {
  __hip_bfloat16 b = __float2bfloat16(f);
  return *reinterpret_cast<ushort_t*>(&b);
}

// ---------------------------------------------------------------------------
// Kernel 0: prep.
//  z in [0,4): transpose + fp32->bf16 cast of the four 512x512 weights into
//              WT[n][k] (k-contig), concatenated [W_l ; W_r] per layer.
//  z == 4   : elementwise fp32->bf16 cast of x (384x512).
// grid (16,16,5), 256 threads
// ---------------------------------------------------------------------------
__global__ __launch_bounds__(256) void prep(
    const float* __restrict__ x,
    const float* __restrict__ w0, const float* __restrict__ w1,
    const float* __restrict__ w2, const float* __restrict__ w3,
    ushort_t* __restrict__ WT0, ushort_t* __restrict__ WT1,
    ushort_t* __restrict__ xb)
{
  const int z = blockIdx.z;
  const int t = threadIdx.x;
  if (z == 4) {
    int idx = (blockIdx.y * 16 + blockIdx.x) * 256 + t;   // 0..65535
#pragma unroll
    for (int r = 0; r < 3; ++r) {
      int i = idx + r * 65536;                            // 3*65536 = 196608
      xb[i] = f2bf(x[i]);
    }
    return;
  }
  __shared__ ushort_t tile[32][33];
  const float* W = (z == 0) ? w0 : (z == 1) ? w1 : (z == 2) ? w2 : w3;
  ushort_t* WT = ((z < 2) ? WT0 : WT1) + (z & 1) * (512 * 512);
  const int n0 = blockIdx.x * 32, k0 = blockIdx.y * 32;
#pragma unroll
  for (int qq = 0; qq < 4; ++qq) {
    int idx = t + qq * 256, r = idx >> 5, c = idx & 31;
    tile[r][c] = f2bf(W[(k0 + r) * 512 + n0 + c]);
  }
  __syncthreads();
#pragma unroll
  for (int qq = 0; qq < 4; ++qq) {
    int idx = t + qq * 256, r = idx >> 5, c = idx & 31;
    WT[(n0 + r) * 512 + k0 + c] = tile[c][r];   // WT[n][k] = bf16(W[k][n])
  }
}

// ---------------------------------------------------------------------------
// Kernel 1/3: dual GEMM  G[m][n] = sum_k A[m][k] * W[k][n],  n in [0,1024)
// A: bf16 [384][512]; WT: bf16 [1024][512] (k-contig rows). Output fp32.
// MFMA 16x16x32_bf16, fragments loaded directly from global (L2-resident).
// grid (24, 8), 256 threads = 4 waves; wave computes 16m x 32n.
// A-frag: lane holds A[m0 + (lane&15)][k = kc*32 + (lane>>4)*8 + j]
// B-frag: lane holds W[k][n0 + (lane&15)] = WT[n0+(lane&15)][k]
// D:      lane writes D[m0 + (lane>>4)*4 + r][n0 + (lane&15)]
// ---------------------------------------------------------------------------
__global__ __launch_bounds__(256) void gemm_mfma(
    const ushort_t* __restrict__ A, const ushort_t* __restrict__ WT,
    float* __restrict__ G)
{
  const int t = threadIdx.x;
  const int wave = t >> 6, lane = t & 63;
  const int lm = lane & 15, q = lane >> 4;
  const int m0 = blockIdx.x * 16;
  const int n0 = (blockIdx.y * 4 + wave) * 32;

  const short8* Ap = (const short8*)A;    // [m][64] short8 chunks
  const short8* Bp = (const short8*)WT;   // [n][64] short8 chunks
  const int arow  = (m0 + lm) * 64 + q;
  const int brow0 = (n0 + lm) * 64 + q;
  const int brow1 = (n0 + 16 + lm) * 64 + q;

  f32x4 acc0 = {0.f, 0.f, 0.f, 0.f};
  f32x4 acc1 = {0.f, 0.f, 0.f, 0.f};
#pragma unroll
  for (int kc = 0; kc < 16; ++kc) {
    short8 af = Ap[arow  + kc * 4];
    short8 b0 = Bp[brow0 + kc * 4];
    short8 b1 = Bp[brow1 + kc * 4];
    acc0 = __builtin_amdgcn_mfma_f32_16x16x32_bf16(af, b0, acc0, 0, 0, 0);
    acc1 = __builtin_amdgcn_mfma_f32_16x16x32_bf16(af, b1, acc1, 0, 0, 0);
  }
#pragma unroll
  for (int r = 0; r < 4; ++r) {
    int m = m0 + q * 4 + r;
    G[m * 1024 + n0 + lm]      = acc0[r];
    G[m * 1024 + n0 + 16 + lm] = acc1[r];
  }
}

// ---------------------------------------------------------------------------
// Kernel 2/4: fused GATv2 attention for an (8-row i-tile, head) pair.
// G: [384][1024] fp32, gl = G[:, :512], gr = G[:, 512:].
// Uses leaky(z) = 0.6 z + 0.4 |z|  =>  e = 0.6*(bl_j + br_i) + 0.4*sum a_f|z|
// LAYER 0: out -> ELU -> + x(fp32)  -> xcur (fp32) and x1b (bf16)
// LAYER 1: out -> + xcur(fp32)      -> d_out (fp32)
// grid (48, 8), 256 threads
// ---------------------------------------------------------------------------
template <int LAYER>
__global__ __launch_bounds__(256) void attn_kernel(
    const float* __restrict__ G, const int* __restrict__ adj,
    const float* __restrict__ resid_in, const float* __restrict__ avec,
    float* __restrict__ xcur_out, ushort_t* __restrict__ x1b_out,
    float* __restrict__ f_out)
{
  __shared__ float s_a[64];
  __shared__ float s_gri[TI][64];
  __shared__ float s_bri[TI];
  __shared__ float s_p[TI][N_NODES];
  __shared__ float s_inv[TI];
  __shared__ float s_agg[4][TI][64];

  const int t  = threadIdx.x;
  const int i0 = blockIdx.x * TI;
  const int h  = blockIdx.y;

  if (t < 64) s_a[t] = avec[t];
  for (int idx = t; idx < TI * 64; idx += 256) {
    int il = idx >> 6, f = idx & 63;
    s_gri[il][f] = G[(i0 + il) * 1024 + 512 + h * 64 + f];
  }
  __syncthreads();
  if (t < TI) {
    float s = 0.f;
#pragma unroll
    for (int f = 0; f < 64; ++f) s += s_a[f] * s_gri[t][f];
    s_bri[t] = s;
  }
  __syncthreads();

  // ---- phase 1: scores (j per thread, 8 i's per block) ----
  const float4* s_a4v = (const float4*)s_a;
  for (int jb = 0; jb < N_NODES; jb += 256) {
    int j = jb + t;
    if (j < N_NODES) {
      const float4* gl4 = (const float4*)(G + j * 1024 + h * 64);
      float accl = 0.f;
      float acca[TI];
#pragma unroll
      for (int il = 0; il < TI; ++il) acca[il] = 0.f;
      for (int c = 0; c < 16; ++c) {
        float4 gv = gl4[c];
        float4 av = s_a4v[c];
        accl += av.x * gv.x + av.y * gv.y + av.z * gv.z + av.w * gv.w;
#pragma unroll
        for (int il = 0; il < TI; ++il) {
          float4 rv = ((const float4*)s_gri[il])[c];
          acca[il] += av.x * fabsf(gv.x + rv.x) + av.y * fabsf(gv.y + rv.y)
                    + av.z * fabsf(gv.z + rv.z) + av.w * fabsf(gv.w + rv.w);
        }
      }
#pragma unroll
      for (int il = 0; il < TI; ++il) {
        int ig = i0 + il;
        bool msk = (adj[ig * N_NODES + j] != 0) || (ig == j);  // self-loop
        float e = 0.6f * (accl + s_bri[il]) + 0.4f * acca[il];
        s_p[il][j] = msk ? e : -1e30f;
      }
    }
  }
  __syncthreads();

  // ---- phase 2: softmax over j (one wave owns each i-row) ----
  const int lane = t & 63, wave = t >> 6;
#pragma unroll
  for (int rep = 0; rep < TI / 4; ++rep) {
    int il = wave + rep * 4;
    float v[6];
    float mx = -1e30f;
#pragma unroll
    for (int c = 0; c < 6; ++c) { v[c] = s_p[il][lane + 64 * c]; mx = fmaxf(mx, v[c]); }
#pragma unroll
    for (int off = 32; off; off >>= 1) mx = fmaxf(mx, __shfl_xor(mx, off));
    float sum = 0.f;
#pragma unroll
    for (int c = 0; c < 6; ++c) {
      float p = __expf(v[c] - mx);
      s_p[il][lane + 64 * c] = p;
      sum += p;
    }
#pragma unroll
    for (int off = 32; off; off >>= 1) sum += __shfl_xor(sum, off);
    if (lane == 0) s_inv[il] = 1.0f / sum;
  }
  __syncthreads();

  // ---- phase 3: aggregate out[i][f] = sum_j p[i][j] * gr[j][f] ----
  {
    const int f = t & 63, wg = t >> 6;
    float acc[TI];
#pragma unroll
    for (int il = 0; il < TI; ++il) acc[il] = 0.f;
    for (int j = wg; j < N_NODES; j += 4) {
      float grv = G[j * 1024 + 512 + h * 64 + f];
#pragma unroll
      for (int il = 0; il < TI; ++il) acc[il] += s_p[il][j] * grv;
    }
#pragma unroll
    for (int il = 0; il < TI; ++il) s_agg[wg][il][f] = acc[il];
  }
  __syncthreads();

  // ---- phase 4: reduce partials + epilogue (act + residual) ----
#pragma unroll
  for (int rep = 0; rep < 2; ++rep) {
    int idx = t + rep * 256;
    int il = idx >> 6, ff = idx & 63;
    float o = (s_agg[0][il][ff] + s_agg[1][il][ff]
             + s_agg[2][il][ff] + s_agg[3][il][ff]) * s_inv[il];
    int ig  = i0 + il;
    int off = ig * HF + h * 64 + ff;
    if (LAYER == 0) {
      float xr = resid_in[off];                       // x, fp32
      float oe = (o > 0.f) ? o : (__expf(o) - 1.f);   // ELU
      float vv = xr + oe;
      xcur_out[off] = vv;          // fp32 residual carried to layer 1
      x1b_out[off]  = f2bf(vv);    // bf16 operand for layer-1 GEMM
    } else {
      f_out[off] = resid_in[off] + o;   // final output, fp32
    }
  }
}

// ---------------------------------------------------------------------------
extern "C" void kernel_launch(void* const* d_in, const int* in_sizes, int n_in,
                              void* d_out, int out_size, void* d_ws, size_t ws_size,
                              hipStream_t stream) {
  const float* x   = (const float*)d_in[0];
  const int*   adj = (const int*)d_in[1];
  const float* Wl0 = (const float*)d_in[2];
  const float* Wr0 = (const float*)d_in[3];
  const float* a0  = (const float*)d_in[4];
  const float* Wl1 = (const float*)d_in[5];
  const float* Wr1 = (const float*)d_in[6];
  const float* a1  = (const float*)d_in[7];
  float* out = (float*)d_out;

  char* ws = (char*)d_ws;
  ushort_t* WT0  = (ushort_t*)(ws);                 // 1 MB  [Wl0;Wr0]^T bf16
  ushort_t* WT1  = (ushort_t*)(ws + 1048576);       // 1 MB  [Wl1;Wr1]^T bf16
  ushort_t* xb   = (ushort_t*)(ws + 2097152);       // 384 KB x bf16
  float*    G    = (float*)   (ws + 2490368);       // 1.5 MB 384x1024 fp32
  float*    xcur = (float*)   (ws + 4063232);       // 768 KB 384x512 fp32
  ushort_t* x1b  = (ushort_t*)(ws + 4849664);       // 384 KB 384x512 bf16
                                                    // total 5 MB

  prep<<<dim3(16, 16, 5), 256, 0, stream>>>(x, Wl0, Wr0, Wl1, Wr1, WT0, WT1, xb);
  gemm_mfma<<<dim3(24, 8), 256, 0, stream>>>(xb, WT0, G);
  attn_kernel<0><<<dim3(48, 8), 256, 0, stream>>>(G, adj, x, a0, xcur, x1b, nullptr);
  gemm_mfma<<<dim3(24, 8), 256, 0, stream>>>(x1b, WT1, G);
  attn_kernel<1><<<dim3(48, 8), 256, 0, stream>>>(G, adj, xcur, a1, nullptr, nullptr, out);
}

// Round 3
// 147.130 us; speedup vs baseline: 1.2205x; 1.2205x over previous
//
#include <hip/hip_runtime.h>
#include <hip/hip_bf16.h>
#include <stdint.h>

typedef unsigned short ushort_t;
typedef __attribute__((ext_vector_type(8))) short short8;   // 8 bf16 (4 VGPRs)
typedef __attribute__((ext_vector_type(4))) float f32x4;

#define N_NODES 384
#define HF      512

__device__ inline ushort_t f2bf(float f) {
  __hip_bfloat16 b = __float2bfloat16(f);
  return *reinterpret_cast<ushort_t*>(&b);
}

// ---------------------------------------------------------------------------
// Kernel 0: prep.
//  z in [0,4): transpose + fp32->bf16 cast of the four 512x512 weights into
//              WT[n][k] (k-contig), concatenated [W_l ; W_r] per layer.
//  z == 4   : elementwise fp32->bf16 cast of x (384x512).
// grid (16,16,5), 256 threads
// ---------------------------------------------------------------------------
__global__ __launch_bounds__(256) void prep(
    const float* __restrict__ x,
    const float* __restrict__ w0, const float* __restrict__ w1,
    const float* __restrict__ w2, const float* __restrict__ w3,
    ushort_t* __restrict__ WT0, ushort_t* __restrict__ WT1,
    ushort_t* __restrict__ xb)
{
  const int z = blockIdx.z;
  const int t = threadIdx.x;
  if (z == 4) {
    int idx = (blockIdx.y * 16 + blockIdx.x) * 256 + t;   // 0..65535
#pragma unroll
    for (int r = 0; r < 3; ++r) {
      int i = idx + r * 65536;                            // 3*65536 = 196608
      xb[i] = f2bf(x[i]);
    }
    return;
  }
  __shared__ ushort_t tile[32][33];
  const float* W = (z == 0) ? w0 : (z == 1) ? w1 : (z == 2) ? w2 : w3;
  ushort_t* WT = ((z < 2) ? WT0 : WT1) + (z & 1) * (512 * 512);
  const int n0 = blockIdx.x * 32, k0 = blockIdx.y * 32;
#pragma unroll
  for (int qq = 0; qq < 4; ++qq) {
    int idx = t + qq * 256, r = idx >> 5, c = idx & 31;
    tile[r][c] = f2bf(W[(k0 + r) * 512 + n0 + c]);
  }
  __syncthreads();
#pragma unroll
  for (int qq = 0; qq < 4; ++qq) {
    int idx = t + qq * 256, r = idx >> 5, c = idx & 31;
    WT[(n0 + r) * 512 + k0 + c] = tile[c][r];   // WT[n][k] = bf16(W[k][n])
  }
}

// ---------------------------------------------------------------------------
// Kernel 1/3: dual GEMM  G[m][n] = sum_k A[m][k] * W[k][n],  n in [0,1024)
// A: bf16 [384][512]; WT: bf16 [1024][512] (k-contig). Output G fp32, plus
// grT bf16 [h][f][j] (k-contig gr^T) for the MFMA aggregation's B-operand.
// grid (24, 8), 256 threads = 4 waves; wave computes 16m x 32n.
// ---------------------------------------------------------------------------
__global__ __launch_bounds__(256) void gemm_mfma(
    const ushort_t* __restrict__ A, const ushort_t* __restrict__ WT,
    float* __restrict__ G, ushort_t* __restrict__ grT)
{
  const int t = threadIdx.x;
  const int wave = t >> 6, lane = t & 63;
  const int lm = lane & 15, q = lane >> 4;
  const int m0 = blockIdx.x * 16;
  const int n0 = (blockIdx.y * 4 + wave) * 32;

  const short8* Ap = (const short8*)A;    // [m][64] short8 chunks
  const short8* Bp = (const short8*)WT;   // [n][64] short8 chunks
  const int arow  = (m0 + lm) * 64 + q;
  const int brow0 = (n0 + lm) * 64 + q;
  const int brow1 = (n0 + 16 + lm) * 64 + q;

  f32x4 acc0 = {0.f, 0.f, 0.f, 0.f};
  f32x4 acc1 = {0.f, 0.f, 0.f, 0.f};
#pragma unroll
  for (int kc = 0; kc < 16; ++kc) {
    short8 af = Ap[arow  + kc * 4];
    short8 b0 = Bp[brow0 + kc * 4];
    short8 b1 = Bp[brow1 + kc * 4];
    acc0 = __builtin_amdgcn_mfma_f32_16x16x32_bf16(af, b0, acc0, 0, 0, 0);
    acc1 = __builtin_amdgcn_mfma_f32_16x16x32_bf16(af, b1, acc1, 0, 0, 0);
  }
#pragma unroll
  for (int r = 0; r < 4; ++r) {
    int m = m0 + q * 4 + r;
    G[m * 1024 + n0 + lm]      = acc0[r];
    G[m * 1024 + n0 + 16 + lm] = acc1[r];
  }
  // gr^T bf16 side-product: grT[(h*64+f)*384 + j] = gr[j][h*64+f]
  if (n0 >= 512) {
    int c0 = n0 - 512;
    uint2 p0, p1;
    p0.x = (uint32_t)f2bf(acc0[0]) | ((uint32_t)f2bf(acc0[1]) << 16);
    p0.y = (uint32_t)f2bf(acc0[2]) | ((uint32_t)f2bf(acc0[3]) << 16);
    p1.x = (uint32_t)f2bf(acc1[0]) | ((uint32_t)f2bf(acc1[1]) << 16);
    p1.y = (uint32_t)f2bf(acc1[2]) | ((uint32_t)f2bf(acc1[3]) << 16);
    *(uint2*)&grT[(c0 + lm) * 384 + m0 + q * 4]      = p0;
    *(uint2*)&grT[(c0 + 16 + lm) * 384 + m0 + q * 4] = p1;
  }
}

// ---------------------------------------------------------------------------
// Kernel 2/4: fused GATv2 attention, one block per (16-row i-tile, head).
// leaky(z) = 0.6 z + 0.4 |z|  =>  e = 0.6*(bl_j + br_i) + 0.4*sum a_f|z|
// Phases: gri/bri -> scores -> softmax (writes P bf16 to LDS) ->
//         MFMA aggregation (A=P from LDS, B=grT from global) -> epilogue.
// LAYER 0: out -> ELU -> + x(fp32)  -> xcur (fp32) and x1b (bf16)
// LAYER 1: out -> + xcur(fp32)      -> d_out (fp32)
// grid (24, 8), 256 threads
// ---------------------------------------------------------------------------
template <int LAYER>
__global__ __launch_bounds__(256) void attn_fused(
    const float* __restrict__ G, const ushort_t* __restrict__ grT,
    const int* __restrict__ adj, const float* __restrict__ resid_in,
    const float* __restrict__ avec,
    float* __restrict__ xcur_out, ushort_t* __restrict__ x1b_out,
    float* __restrict__ f_out)
{
  __shared__ float s_a[64];
  __shared__ float s_gri[16][64];
  __shared__ float s_bri[16];
  __shared__ float s_e[16][N_NODES];     // 24 KB
  __shared__ ushort_t s_pb[16][392];     // +8 pad: 2-way-free LDS banks

  const int t = threadIdx.x, lane = t & 63, wave = t >> 6;
  const int i0 = blockIdx.x * 16, h = blockIdx.y;

  if (t < 64) s_a[t] = avec[t];
  {
    int il = t >> 4, c = t & 15;   // 16 rows x 16 float4
    ((float4*)s_gri[il])[c] =
        *(const float4*)(G + (i0 + il) * 1024 + 512 + h * 64 + c * 4);
  }
  __syncthreads();
  if (t < 128) {                   // bri[row] = a . gr_i, 8 threads/row
    int row = t >> 3, g = t & 7;
    float s = 0.f;
#pragma unroll
    for (int f = 0; f < 8; ++f) s += s_a[g * 8 + f] * s_gri[row][g * 8 + f];
    s += __shfl_xor(s, 1); s += __shfl_xor(s, 2); s += __shfl_xor(s, 4);
    if (g == 0) s_bri[row] = s;
  }
  __syncthreads();

  // ---- phase 1: scores (j per thread, 16 i's per block) ----
  for (int jb = 0; jb < N_NODES; jb += 256) {
    int j = jb + t;
    if (j < N_NODES) {
      const float4* gl4 = (const float4*)(G + j * 1024 + h * 64);
      float accl = 0.f;
      float acca[16];
#pragma unroll
      for (int il = 0; il < 16; ++il) acca[il] = 0.f;
#pragma unroll 4
      for (int c = 0; c < 16; ++c) {
        float4 gv = gl4[c];
        float4 av = ((const float4*)s_a)[c];
        accl += av.x * gv.x + av.y * gv.y + av.z * gv.z + av.w * gv.w;
#pragma unroll
        for (int il = 0; il < 16; ++il) {
          float4 rv = ((const float4*)s_gri[il])[c];
          acca[il] += av.x * fabsf(gv.x + rv.x) + av.y * fabsf(gv.y + rv.y)
                    + av.z * fabsf(gv.z + rv.z) + av.w * fabsf(gv.w + rv.w);
        }
      }
#pragma unroll
      for (int il = 0; il < 16; ++il) {
        int ig = i0 + il;
        bool msk = (adj[ig * N_NODES + j] != 0) || (ig == j);  // self-loop
        float e = 0.6f * (accl + s_bri[il]) + 0.4f * acca[il];
        s_e[il][j] = msk ? e : -1e30f;
      }
    }
  }
  __syncthreads();

  // ---- phase 2: softmax over j; write normalized P as bf16 ----
#pragma unroll
  for (int rep = 0; rep < 4; ++rep) {
    int il = wave * 4 + rep;
    float v[6];
    float mx = -1e30f;
#pragma unroll
    for (int c = 0; c < 6; ++c) { v[c] = s_e[il][lane + 64 * c]; mx = fmaxf(mx, v[c]); }
#pragma unroll
    for (int off = 32; off; off >>= 1) mx = fmaxf(mx, __shfl_xor(mx, off));
    float sum = 0.f;
#pragma unroll
    for (int c = 0; c < 6; ++c) { v[c] = __expf(v[c] - mx); sum += v[c]; }
#pragma unroll
    for (int off = 32; off; off >>= 1) sum += __shfl_xor(sum, off);
    float inv = 1.0f / sum;
#pragma unroll
    for (int c = 0; c < 6; ++c) s_pb[il][lane + 64 * c] = f2bf(v[c] * inv);
  }
  __syncthreads();

  // ---- phase 3: MFMA aggregation  out[16 i][64 f] = P[16][384] @ gr[384][64]
  {
    const int lm = lane & 15, q = lane >> 4;
    const int f0 = wave * 16;                       // wave owns a 16-f tile
    const ushort_t* Brow = grT + (h * 64 + f0 + lm) * 384;
    f32x4 acc = {0.f, 0.f, 0.f, 0.f};
#pragma unroll
    for (int kc = 0; kc < 12; ++kc) {
      short8 af = *(const short8*)&s_pb[lm][kc * 32 + q * 8];
      short8 bf = *(const short8*)&Brow[kc * 32 + q * 8];
      acc = __builtin_amdgcn_mfma_f32_16x16x32_bf16(af, bf, acc, 0, 0, 0);
    }
#pragma unroll
    for (int r = 0; r < 4; ++r) {
      int i = i0 + q * 4 + r;
      int off = i * HF + h * 64 + f0 + lm;
      float o = acc[r];
      if (LAYER == 0) {
        float oe = (o > 0.f) ? o : (__expf(o) - 1.f);   // ELU
        float vv = resid_in[off] + oe;
        xcur_out[off] = vv;          // fp32 residual for layer 1
        x1b_out[off]  = f2bf(vv);    // bf16 operand for layer-1 GEMM
      } else {
        f_out[off] = resid_in[off] + o;   // final output, fp32
      }
    }
  }
}

// ---------------------------------------------------------------------------
extern "C" void kernel_launch(void* const* d_in, const int* in_sizes, int n_in,
                              void* d_out, int out_size, void* d_ws, size_t ws_size,
                              hipStream_t stream) {
  const float* x   = (const float*)d_in[0];
  const int*   adj = (const int*)d_in[1];
  const float* Wl0 = (const float*)d_in[2];
  const float* Wr0 = (const float*)d_in[3];
  const float* a0  = (const float*)d_in[4];
  const float* Wl1 = (const float*)d_in[5];
  const float* Wr1 = (const float*)d_in[6];
  const float* a1  = (const float*)d_in[7];
  float* out = (float*)d_out;

  char* ws = (char*)d_ws;
  // xcur aliases WT0: WT0 is consumed by gemm0 before attn0 writes xcur
  // (single-stream ordering), so the 1 MB region is reused.
  float*    xcur = (float*)(ws);                    // 768 KB (alias of WT0)
  ushort_t* WT0  = (ushort_t*)(ws);                 // 1 MB  [Wl0;Wr0]^T bf16
  ushort_t* WT1  = (ushort_t*)(ws + 1048576);       // 1 MB  [Wl1;Wr1]^T bf16
  ushort_t* xb   = (ushort_t*)(ws + 2097152);       // 384 KB x bf16
  float*    G    = (float*)   (ws + 2490368);       // 1.5 MB 384x1024 fp32
  ushort_t* grT  = (ushort_t*)(ws + 4063232);       // 384 KB gr^T bf16
  ushort_t* x1b  = (ushort_t*)(ws + 4456448);       // 384 KB 384x512 bf16
                                                    // total 4.85 MB (<= 5 MB proven)

  prep<<<dim3(16, 16, 5), 256, 0, stream>>>(x, Wl0, Wr0, Wl1, Wr1, WT0, WT1, xb);
  gemm_mfma<<<dim3(24, 8), 256, 0, stream>>>(xb, WT0, G, grT);
  attn_fused<0><<<dim3(24, 8), 256, 0, stream>>>(G, grT, adj, x, a0,
                                                 xcur, x1b, nullptr);
  gemm_mfma<<<dim3(24, 8), 256, 0, stream>>>(x1b, WT1, G, grT);
  attn_fused<1><<<dim3(24, 8), 256, 0, stream>>>(G, grT, adj, xcur, a1,
                                                 nullptr, nullptr, out);
}

// Round 4
// 136.960 us; speedup vs baseline: 1.3112x; 1.0743x over previous
//
#include <hip/hip_runtime.h>
#include <hip/hip_bf16.h>
#include <stdint.h>

typedef unsigned short ushort_t;
typedef unsigned long long u64;
typedef __attribute__((ext_vector_type(8))) short short8;   // 8 bf16 (4 VGPRs)
typedef __attribute__((ext_vector_type(4))) float f32x4;

#define N_NODES 384
#define HF      512

__device__ inline ushort_t f2bf(float f) {
  __hip_bfloat16 b = __float2bfloat16(f);
  return *reinterpret_cast<ushort_t*>(&b);
}
__device__ inline float bf2f_u(ushort_t u) {
  union { float f; uint32_t i; } v; v.i = ((uint32_t)u) << 16; return v.f;
}

// ---------------------------------------------------------------------------
// Kernel 0: prep.
//  z in [0,4): transpose + fp32->bf16 cast of the four 512x512 weights into
//              WT[n][k] (k-contig), concat [W_l ; W_r] per layer.
//  z == 4   : elementwise fp32->bf16 cast of x (384x512).
//  z == 5   : adjacency -> bitmasks mbits[row*6+w], self-loop OR'd in.
// grid (16,16,6), 256 threads
// ---------------------------------------------------------------------------
__global__ __launch_bounds__(256) void prep(
    const float* __restrict__ x, const int* __restrict__ adj,
    const float* __restrict__ w0, const float* __restrict__ w1,
    const float* __restrict__ w2, const float* __restrict__ w3,
    ushort_t* __restrict__ WT0, ushort_t* __restrict__ WT1,
    ushort_t* __restrict__ xb, u64* __restrict__ mbits)
{
  const int z = blockIdx.z;
  const int t = threadIdx.x;
  if (z == 4) {
    int idx = (blockIdx.y * 16 + blockIdx.x) * 256 + t;   // 0..65535
#pragma unroll
    for (int r = 0; r < 3; ++r) {
      int i = idx + r * 65536;                            // 3*65536 = 196608
      xb[i] = f2bf(x[i]);
    }
    return;
  }
  if (z == 5) {
    int b = blockIdx.y * 16 + blockIdx.x;
    if (b >= 96) return;                                  // 96 blocks * 4 rows
    int wave = t >> 6, lane = t & 63;
    int row = b * 4 + wave;
#pragma unroll
    for (int w = 0; w < 6; ++w) {
      int j = w * 64 + lane;
      int v = adj[row * N_NODES + j];
      u64 m = __ballot(v != 0 || row == j);
      if (lane == 0) mbits[row * 6 + w] = m;
    }
    return;
  }
  __shared__ ushort_t tile[32][33];
  const float* W = (z == 0) ? w0 : (z == 1) ? w1 : (z == 2) ? w2 : w3;
  ushort_t* WT = ((z < 2) ? WT0 : WT1) + (z & 1) * (512 * 512);
  const int n0 = blockIdx.x * 32, k0 = blockIdx.y * 32;
#pragma unroll
  for (int qq = 0; qq < 4; ++qq) {
    int idx = t + qq * 256, r = idx >> 5, c = idx & 31;
    tile[r][c] = f2bf(W[(k0 + r) * 512 + n0 + c]);
  }
  __syncthreads();
#pragma unroll
  for (int qq = 0; qq < 4; ++qq) {
    int idx = t + qq * 256, r = idx >> 5, c = idx & 31;
    WT[(n0 + r) * 512 + k0 + c] = tile[c][r];   // WT[n][k] = bf16(W[k][n])
  }
}

// ---------------------------------------------------------------------------
// Kernel 1/3: dual GEMM over n in [0,1024).
//  n <  512 (gl): write glb bf16 [m][n]           (attn phase-1 A-side)
//  n >= 512 (gr): write G fp32 [m][512+ n'] and grT bf16 [n'][m] (k-contig)
// grid (24, 8), 256 threads = 4 waves; wave computes 16m x 32n.
// ---------------------------------------------------------------------------
__global__ __launch_bounds__(256) void gemm_mfma(
    const ushort_t* __restrict__ A, const ushort_t* __restrict__ WT,
    float* __restrict__ G, ushort_t* __restrict__ glb,
    ushort_t* __restrict__ grT)
{
  const int t = threadIdx.x;
  const int wave = t >> 6, lane = t & 63;
  const int lm = lane & 15, q = lane >> 4;
  const int m0 = blockIdx.x * 16;
  const int n0 = (blockIdx.y * 4 + wave) * 32;

  const short8* Ap = (const short8*)A;    // [m][64] short8 chunks
  const short8* Bp = (const short8*)WT;   // [n][64] short8 chunks
  const int arow  = (m0 + lm) * 64 + q;
  const int brow0 = (n0 + lm) * 64 + q;
  const int brow1 = (n0 + 16 + lm) * 64 + q;

  f32x4 acc0 = {0.f, 0.f, 0.f, 0.f};
  f32x4 acc1 = {0.f, 0.f, 0.f, 0.f};
#pragma unroll
  for (int kc = 0; kc < 16; ++kc) {
    short8 af = Ap[arow  + kc * 4];
    short8 b0 = Bp[brow0 + kc * 4];
    short8 b1 = Bp[brow1 + kc * 4];
    acc0 = __builtin_amdgcn_mfma_f32_16x16x32_bf16(af, b0, acc0, 0, 0, 0);
    acc1 = __builtin_amdgcn_mfma_f32_16x16x32_bf16(af, b1, acc1, 0, 0, 0);
  }
  if (n0 < 512) {
#pragma unroll
    for (int r = 0; r < 4; ++r) {
      int m = m0 + q * 4 + r;
      glb[m * HF + n0 + lm]      = f2bf(acc0[r]);
      glb[m * HF + n0 + 16 + lm] = f2bf(acc1[r]);
    }
  } else {
#pragma unroll
    for (int r = 0; r < 4; ++r) {
      int m = m0 + q * 4 + r;
      G[m * 1024 + n0 + lm]      = acc0[r];
      G[m * 1024 + n0 + 16 + lm] = acc1[r];
    }
    int c0 = n0 - 512;
    uint2 p0, p1;
    p0.x = (uint32_t)f2bf(acc0[0]) | ((uint32_t)f2bf(acc0[1]) << 16);
    p0.y = (uint32_t)f2bf(acc0[2]) | ((uint32_t)f2bf(acc0[3]) << 16);
    p1.x = (uint32_t)f2bf(acc1[0]) | ((uint32_t)f2bf(acc1[1]) << 16);
    p1.y = (uint32_t)f2bf(acc1[2]) | ((uint32_t)f2bf(acc1[3]) << 16);
    *(uint2*)&grT[(c0 + lm) * 384 + m0 + q * 4]      = p0;
    *(uint2*)&grT[(c0 + 16 + lm) * 384 + m0 + q * 4] = p1;
  }
}

// ---------------------------------------------------------------------------
// Kernel 2/4: fused GATv2 attention. Block = (16-row i-tile, head), 384 thr.
// Thread t == source node j. leaky(z) = 0.6 z + 0.4 |z|.
// Phase 1: gl_j in 64 VGPRs (from LDS-staged glb); gr_il[f], a[f] via
//          wave-uniform loads (SGPRs) -> inner loop is pure VALU.
// Phase 2: softmax rows; P bf16 -> LDS. Phase 3: MFMA P @ gr. Epilogue fused.
// grid (24, 8), 384 threads
// ---------------------------------------------------------------------------
template <int LAYER>
__global__ __launch_bounds__(384) void attn_fused(
    const float* __restrict__ G, const ushort_t* __restrict__ glb,
    const ushort_t* __restrict__ grT, const u64* __restrict__ mbits,
    const float* __restrict__ resid_in, const float* __restrict__ avec,
    float* __restrict__ xcur_out, ushort_t* __restrict__ x1b_out,
    float* __restrict__ f_out)
{
  // s_gl [384][72] bf16 = 55296 B, barrier-aliased with {s_e fp32 16x384
  // (24576) + s_pb bf16 16x392 (12544) = 37120 B}.
  __shared__ __align__(16) char smem[55296];
  ushort_t (*s_gl)[72]      = (ushort_t(*)[72])smem;
  float    (*s_e)[N_NODES]  = (float(*)[N_NODES])smem;
  ushort_t (*s_pb)[392]     = (ushort_t(*)[392])(smem + 24576);
  __shared__ float s_bri[16];
  __shared__ u64   s_mask[16][6];

  const int t = threadIdx.x;
  const int i0 = blockIdx.x * 16, h = blockIdx.y;
  const int lane = t & 63, wave = t >> 6;

  // -- phase 0a: small stages (masks) + bri dot (threads 128..383) --
  if (t >= 64 && t < 160) ((u64*)s_mask)[t - 64] = mbits[i0 * 6 + (t - 64)];
  if (t >= 128) {
    int u = t - 128, il = u >> 4, fg = u & 15;
    float4 g4 = *(const float4*)(G + (i0 + il) * 1024 + 512 + h * 64 + fg * 4);
    float4 a4 = *(const float4*)(avec + fg * 4);
    float s = a4.x * g4.x + a4.y * g4.y + a4.z * g4.z + a4.w * g4.w;
    s += __shfl_xor(s, 1); s += __shfl_xor(s, 2);
    s += __shfl_xor(s, 4); s += __shfl_xor(s, 8);
    if (fg == 0) s_bri[il] = s;
  }
  // -- phase 0b: stage all gl rows (bf16) coalesced into LDS --
#pragma unroll
  for (int rep = 0; rep < 8; ++rep) {
    int idx = rep * 384 + t, row = idx >> 3, c = idx & 7;
    *(short8*)&s_gl[row][c * 8] =
        *(const short8*)&glb[row * HF + h * 64 + c * 8];
  }
  __syncthreads();

  // -- extract own j-row into 64 VGPRs --
  float gl[64];
  {
    const short8* rowp = (const short8*)&s_gl[t][0];
#pragma unroll
    for (int c = 0; c < 8; ++c) {
      short8 v = rowp[c];
#pragma unroll
      for (int u2 = 0; u2 < 8; ++u2)
        gl[c * 8 + u2] = bf2f_u((ushort_t)v[u2]);
    }
  }
  __syncthreads();   // s_gl region now reusable for s_e / s_pb

  // -- phase 1: scores. accl = a . gl (SGPR a); per il: sum a_f |gl+gr| --
  float accl = 0.f;
#pragma unroll
  for (int f = 0; f < 64; ++f) accl += avec[f] * gl[f];

  float e_abs[16];
  for (int il = 0; il < 16; ++il) {
    const float* __restrict__ gr = G + (i0 + il) * 1024 + 512 + h * 64;
    float acc = 0.f;
#pragma unroll
    for (int f = 0; f < 64; ++f) {
      float z = gl[f] + gr[f];          // v + s
      acc += avec[f] * fabsf(z);        // v_fma s, |v|, acc
    }
    e_abs[il] = acc;
  }
  {
    const int jw = t >> 6, jb = t & 63;
#pragma unroll
    for (int il = 0; il < 16; ++il) {
      bool m = (s_mask[il][jw] >> jb) & 1;
      float e = 0.6f * (accl + s_bri[il]) + 0.4f * e_abs[il];
      s_e[il][t] = m ? e : -1e30f;
    }
  }
  __syncthreads();

  // -- phase 2: softmax over j per row; write normalized P bf16 --
  for (int il = wave; il < 16; il += 6) {
    float v[6];
    float mx = -1e30f;
#pragma unroll
    for (int c = 0; c < 6; ++c) { v[c] = s_e[il][lane + 64 * c]; mx = fmaxf(mx, v[c]); }
#pragma unroll
    for (int off = 32; off; off >>= 1) mx = fmaxf(mx, __shfl_xor(mx, off));
    float sum = 0.f;
#pragma unroll
    for (int c = 0; c < 6; ++c) { v[c] = __expf(v[c] - mx); sum += v[c]; }
#pragma unroll
    for (int off = 32; off; off >>= 1) sum += __shfl_xor(sum, off);
    float inv = 1.0f / sum;
#pragma unroll
    for (int c = 0; c < 6; ++c) s_pb[il][lane + 64 * c] = f2bf(v[c] * inv);
  }
  __syncthreads();

  // -- phase 3: MFMA aggregation out[16 i][64 f] = P[16][384] @ gr[384][64]
  if (t < 256) {
    const int lm = lane & 15, q = lane >> 4;
    const int f0 = wave * 16;                       // waves 0..3: 16-f tiles
    const ushort_t* Brow = grT + (h * 64 + f0 + lm) * 384;
    f32x4 acc = {0.f, 0.f, 0.f, 0.f};
#pragma unroll
    for (int kc = 0; kc < 12; ++kc) {
      short8 af = *(const short8*)&s_pb[lm][kc * 32 + q * 8];
      short8 bf = *(const short8*)&Brow[kc * 32 + q * 8];
      acc = __builtin_amdgcn_mfma_f32_16x16x32_bf16(af, bf, acc, 0, 0, 0);
    }
#pragma unroll
    for (int r = 0; r < 4; ++r) {
      int i = i0 + q * 4 + r;
      int off = i * HF + h * 64 + f0 + lm;
      float o = acc[r];
      if (LAYER == 0) {
        float oe = (o > 0.f) ? o : (__expf(o) - 1.f);   // ELU
        float vv = resid_in[off] + oe;
        xcur_out[off] = vv;          // fp32 residual for layer 1
        x1b_out[off]  = f2bf(vv);    // bf16 operand for layer-1 GEMM
      } else {
        f_out[off] = resid_in[off] + o;   // final output, fp32
      }
    }
  }
}

// ---------------------------------------------------------------------------
extern "C" void kernel_launch(void* const* d_in, const int* in_sizes, int n_in,
                              void* d_out, int out_size, void* d_ws, size_t ws_size,
                              hipStream_t stream) {
  const float* x   = (const float*)d_in[0];
  const int*   adj = (const int*)d_in[1];
  const float* Wl0 = (const float*)d_in[2];
  const float* Wr0 = (const float*)d_in[3];
  const float* a0  = (const float*)d_in[4];
  const float* Wl1 = (const float*)d_in[5];
  const float* Wr1 = (const float*)d_in[6];
  const float* a1  = (const float*)d_in[7];
  float* out = (float*)d_out;

  char* ws = (char*)d_ws;                       // ws is 256 MiB — spread out
  ushort_t* WT0  = (ushort_t*)(ws + 0L);        // 1 MB  [Wl0;Wr0]^T bf16
  ushort_t* WT1  = (ushort_t*)(ws + (1L << 20));    // 1 MB
  ushort_t* xb   = (ushort_t*)(ws + (2L << 20));    // 384 KB x bf16
  float*    G    = (float*)   (ws + (3L << 20));    // 1.5 MB (gr half used)
  ushort_t* grT  = (ushort_t*)(ws + (5L << 20));    // 384 KB gr^T bf16
  ushort_t* x1b  = (ushort_t*)(ws + (6L << 20));    // 384 KB
  ushort_t* glb  = (ushort_t*)(ws + (7L << 20));    // 384 KB gl bf16
  u64*      mbits= (u64*)     (ws + (8L << 20));    // 18 KB adjacency bits
  float*    xcur = (float*)   (ws + (9L << 20));    // 768 KB fp32 residual

  prep<<<dim3(16, 16, 6), 256, 0, stream>>>(x, adj, Wl0, Wr0, Wl1, Wr1,
                                            WT0, WT1, xb, mbits);
  gemm_mfma<<<dim3(24, 8), 256, 0, stream>>>(xb, WT0, G, glb, grT);
  attn_fused<0><<<dim3(24, 8), 384, 0, stream>>>(G, glb, grT, mbits, x, a0,
                                                 xcur, x1b, nullptr);
  gemm_mfma<<<dim3(24, 8), 256, 0, stream>>>(x1b, WT1, G, glb, grT);
  attn_fused<1><<<dim3(24, 8), 384, 0, stream>>>(G, glb, grT, mbits, xcur, a1,
                                                 nullptr, nullptr, out);
}

// Round 5
// 131.467 us; speedup vs baseline: 1.3660x; 1.0418x over previous
//
#include <hip/hip_runtime.h>
#include <hip/hip_bf16.h>
#include <stdint.h>

typedef unsigned short ushort_t;
typedef unsigned long long u64;
typedef __attribute__((ext_vector_type(8))) short short8;   // 8 bf16 (4 VGPRs)
typedef __attribute__((ext_vector_type(4))) float f32x4;

#define N_NODES 384
#define HF      512

__device__ inline ushort_t f2bf(float f) {
  __hip_bfloat16 b = __float2bfloat16(f);
  return *reinterpret_cast<ushort_t*>(&b);
}
__device__ inline float bf2f_u(ushort_t u) {
  union { float f; uint32_t i; } v; v.i = ((uint32_t)u) << 16; return v.f;
}

// ---------------------------------------------------------------------------
// Kernel 0: prep.
//  z in [0,4): transpose + fp32->bf16 cast of the four 512x512 weights into
//              WT[n][k] (k-contig), concat [W_l ; W_r] per layer.
//  z == 4   : elementwise fp32->bf16 cast of x (384x512).
//  z == 5   : adjacency -> bitmasks mbits[row*6+w], self-loop OR'd in.
// grid (16,16,6), 256 threads
// ---------------------------------------------------------------------------
__global__ __launch_bounds__(256) void prep(
    const float* __restrict__ x, const int* __restrict__ adj,
    const float* __restrict__ w0, const float* __restrict__ w1,
    const float* __restrict__ w2, const float* __restrict__ w3,
    ushort_t* __restrict__ WT0, ushort_t* __restrict__ WT1,
    ushort_t* __restrict__ xb, u64* __restrict__ mbits)
{
  const int z = blockIdx.z;
  const int t = threadIdx.x;
  if (z == 4) {
    int idx = (blockIdx.y * 16 + blockIdx.x) * 256 + t;   // 0..65535
#pragma unroll
    for (int r = 0; r < 3; ++r) {
      int i = idx + r * 65536;                            // 3*65536 = 196608
      xb[i] = f2bf(x[i]);
    }
    return;
  }
  if (z == 5) {
    int b = blockIdx.y * 16 + blockIdx.x;
    if (b >= 96) return;                                  // 96 blocks * 4 rows
    int wave = t >> 6, lane = t & 63;
    int row = b * 4 + wave;
#pragma unroll
    for (int w = 0; w < 6; ++w) {
      int j = w * 64 + lane;
      int v = adj[row * N_NODES + j];
      u64 m = __ballot(v != 0 || row == j);
      if (lane == 0) mbits[row * 6 + w] = m;
    }
    return;
  }
  __shared__ ushort_t tile[32][33];
  const float* W = (z == 0) ? w0 : (z == 1) ? w1 : (z == 2) ? w2 : w3;
  ushort_t* WT = ((z < 2) ? WT0 : WT1) + (z & 1) * (512 * 512);
  const int n0 = blockIdx.x * 32, k0 = blockIdx.y * 32;
#pragma unroll
  for (int qq = 0; qq < 4; ++qq) {
    int idx = t + qq * 256, r = idx >> 5, c = idx & 31;
    tile[r][c] = f2bf(W[(k0 + r) * 512 + n0 + c]);
  }
  __syncthreads();
#pragma unroll
  for (int qq = 0; qq < 4; ++qq) {
    int idx = t + qq * 256, r = idx >> 5, c = idx & 31;
    WT[(n0 + r) * 512 + k0 + c] = tile[c][r];   // WT[n][k] = bf16(W[k][n])
  }
}

// ---------------------------------------------------------------------------
// Kernel 1/3: dual GEMM over n in [0,1024).
//  n <  512 (gl): write glb bf16 [m][n]           (attn phase-1 A-side)
//  n >= 512 (gr): write G fp32 [m][512+ n'] and grT bf16 [n'][m] (k-contig)
// grid (24, 8), 256 threads = 4 waves; wave computes 16m x 32n.
// ---------------------------------------------------------------------------
__global__ __launch_bounds__(256) void gemm_mfma(
    const ushort_t* __restrict__ A, const ushort_t* __restrict__ WT,
    float* __restrict__ G, ushort_t* __restrict__ glb,
    ushort_t* __restrict__ grT)
{
  const int t = threadIdx.x;
  const int wave = t >> 6, lane = t & 63;
  const int lm = lane & 15, q = lane >> 4;
  const int m0 = blockIdx.x * 16;
  const int n0 = (blockIdx.y * 4 + wave) * 32;

  const short8* Ap = (const short8*)A;    // [m][64] short8 chunks
  const short8* Bp = (const short8*)WT;   // [n][64] short8 chunks
  const int arow  = (m0 + lm) * 64 + q;
  const int brow0 = (n0 + lm) * 64 + q;
  const int brow1 = (n0 + 16 + lm) * 64 + q;

  f32x4 acc0 = {0.f, 0.f, 0.f, 0.f};
  f32x4 acc1 = {0.f, 0.f, 0.f, 0.f};
#pragma unroll
  for (int kc = 0; kc < 16; ++kc) {
    short8 af = Ap[arow  + kc * 4];
    short8 b0 = Bp[brow0 + kc * 4];
    short8 b1 = Bp[brow1 + kc * 4];
    acc0 = __builtin_amdgcn_mfma_f32_16x16x32_bf16(af, b0, acc0, 0, 0, 0);
    acc1 = __builtin_amdgcn_mfma_f32_16x16x32_bf16(af, b1, acc1, 0, 0, 0);
  }
  if (n0 < 512) {
#pragma unroll
    for (int r = 0; r < 4; ++r) {
      int m = m0 + q * 4 + r;
      glb[m * HF + n0 + lm]      = f2bf(acc0[r]);
      glb[m * HF + n0 + 16 + lm] = f2bf(acc1[r]);
    }
  } else {
#pragma unroll
    for (int r = 0; r < 4; ++r) {
      int m = m0 + q * 4 + r;
      G[m * 1024 + n0 + lm]      = acc0[r];
      G[m * 1024 + n0 + 16 + lm] = acc1[r];
    }
    int c0 = n0 - 512;
    uint2 p0, p1;
    p0.x = (uint32_t)f2bf(acc0[0]) | ((uint32_t)f2bf(acc0[1]) << 16);
    p0.y = (uint32_t)f2bf(acc0[2]) | ((uint32_t)f2bf(acc0[3]) << 16);
    p1.x = (uint32_t)f2bf(acc1[0]) | ((uint32_t)f2bf(acc1[1]) << 16);
    p1.y = (uint32_t)f2bf(acc1[2]) | ((uint32_t)f2bf(acc1[3]) << 16);
    *(uint2*)&grT[(c0 + lm) * 384 + m0 + q * 4]      = p0;
    *(uint2*)&grT[(c0 + 16 + lm) * 384 + m0 + q * 4] = p1;
  }
}

// ---------------------------------------------------------------------------
// Kernel 2/4: fused GATv2 attention. Block = (8-row i-tile, head), 384 thr.
// Thread t == source node j. leaky(z) = 0.6 z + 0.4 |z|.
// Phase 1 is pure-register VALU: gl_j and avec in VGPRs, gr via uniform
// float4 loads, scores written straight to LDS (no private arrays -> no
// scratch). Phase 2: softmax; P bf16 -> LDS (rows 8..15 zeroed).
// Phase 3: MFMA P @ grT. Epilogue fused.
// grid (48, 8), 384 threads
// ---------------------------------------------------------------------------
template <int LAYER>
__global__ __launch_bounds__(384) void attn_fused(
    const float* __restrict__ G, const ushort_t* __restrict__ glb,
    const ushort_t* __restrict__ grT, const u64* __restrict__ mbits,
    const float* __restrict__ resid_in, const float* __restrict__ avec,
    float* __restrict__ xcur_out, ushort_t* __restrict__ x1b_out,
    float* __restrict__ f_out)
{
  // s_gl [384][72] bf16 = 55296 B, barrier-aliased with
  // { s_e fp32 8x384 (12288) + s_pb bf16 16x392 (12544) }.
  __shared__ __align__(16) char smem[55296];
  ushort_t (*s_gl)[72]      = (ushort_t(*)[72])smem;
  float    (*s_e)[N_NODES]  = (float(*)[N_NODES])smem;
  ushort_t (*s_pb)[392]     = (ushort_t(*)[392])(smem + 12288);
  __shared__ float s_bri[8];
  __shared__ u64   s_mask[8][6];

  const int t = threadIdx.x;
  const int i0 = blockIdx.x * 8, h = blockIdx.y;
  const int lane = t & 63, wave = t >> 6;

  // -- phase 0a: masks (48 u64) + bri dot (threads 128..255) --
  if (t >= 256 && t < 304) ((u64*)s_mask)[t - 256] = mbits[i0 * 6 + (t - 256)];
  if (t >= 128 && t < 256) {
    int u = t - 128, il = u >> 4, fg = u & 15;
    float4 g4 = *(const float4*)(G + (i0 + il) * 1024 + 512 + h * 64 + fg * 4);
    float4 a4 = *(const float4*)(avec + fg * 4);
    float s = a4.x * g4.x + a4.y * g4.y + a4.z * g4.z + a4.w * g4.w;
    s += __shfl_xor(s, 1); s += __shfl_xor(s, 2);
    s += __shfl_xor(s, 4); s += __shfl_xor(s, 8);
    if (fg == 0) s_bri[il] = s;
  }
  // -- phase 0b: stage all 384 gl rows (bf16) coalesced into LDS --
#pragma unroll
  for (int rep = 0; rep < 8; ++rep) {
    int idx = rep * 384 + t, row = idx >> 3, c = idx & 7;
    *(short8*)&s_gl[row][c * 8] =
        *(const short8*)&glb[row * HF + h * 64 + c * 8];
  }
  __syncthreads();

  // -- own j-row -> 64 VGPRs; avec -> 64 VGPRs --
  float gl[64], av[64];
  {
    const short8* rowp = (const short8*)&s_gl[t][0];
#pragma unroll
    for (int c = 0; c < 8; ++c) {
      short8 v = rowp[c];
#pragma unroll
      for (int u2 = 0; u2 < 8; ++u2)
        gl[c * 8 + u2] = bf2f_u((ushort_t)v[u2]);
    }
#pragma unroll
    for (int c = 0; c < 16; ++c) {
      float4 a4 = ((const float4*)avec)[c];
      av[c * 4] = a4.x; av[c * 4 + 1] = a4.y;
      av[c * 4 + 2] = a4.z; av[c * 4 + 3] = a4.w;
    }
  }
  float accl = 0.f;
#pragma unroll
  for (int f = 0; f < 64; ++f) accl += av[f] * gl[f];
  __syncthreads();   // s_gl dead; region becomes s_e / s_pb

  // -- phase 1: scores, written straight to LDS (no private arrays) --
  const int jw = t >> 6, jb = t & 63;
#pragma unroll
  for (int il = 0; il < 8; ++il) {
    const float4* gr4 = (const float4*)(G + (i0 + il) * 1024 + 512 + h * 64);
    float acc = 0.f;
#pragma unroll
    for (int c = 0; c < 16; ++c) {
      float4 g4 = gr4[c];
      acc += av[c * 4]     * fabsf(gl[c * 4]     + g4.x);
      acc += av[c * 4 + 1] * fabsf(gl[c * 4 + 1] + g4.y);
      acc += av[c * 4 + 2] * fabsf(gl[c * 4 + 2] + g4.z);
      acc += av[c * 4 + 3] * fabsf(gl[c * 4 + 3] + g4.w);
    }
    bool m = (s_mask[il][jw] >> jb) & 1;
    float e = 0.6f * (accl + s_bri[il]) + 0.4f * acc;
    s_e[il][t] = m ? e : -1e30f;
  }
  // zero P rows 8..15 (MFMA A-operand padding); cols 384..391 unused
  {
    ushort_t z0 = 0;
#pragma unroll
    for (int r8 = 0; r8 < 8; ++r8) s_pb[8 + r8][t] = z0;
  }
  __syncthreads();

  // -- phase 2: softmax over j per row; write normalized P bf16 --
  for (int il = wave; il < 8; il += 6) {
    float v[6];
    float mx = -1e30f;
#pragma unroll
    for (int c = 0; c < 6; ++c) { v[c] = s_e[il][lane + 64 * c]; mx = fmaxf(mx, v[c]); }
#pragma unroll
    for (int off = 32; off; off >>= 1) mx = fmaxf(mx, __shfl_xor(mx, off));
    float sum = 0.f;
#pragma unroll
    for (int c = 0; c < 6; ++c) { v[c] = __expf(v[c] - mx); sum += v[c]; }
#pragma unroll
    for (int off = 32; off; off >>= 1) sum += __shfl_xor(sum, off);
    float inv = 1.0f / sum;
#pragma unroll
    for (int c = 0; c < 6; ++c) s_pb[il][lane + 64 * c] = f2bf(v[c] * inv);
  }
  __syncthreads();

  // -- phase 3: MFMA aggregation out[8 i][64 f] = P[8][384] @ gr[384][64] --
  if (t < 256) {
    const int lm = lane & 15, q = lane >> 4;
    const int f0 = wave * 16;                       // waves 0..3: 16-f tiles
    const ushort_t* Brow = grT + (h * 64 + f0 + lm) * 384;
    f32x4 acc = {0.f, 0.f, 0.f, 0.f};
#pragma unroll
    for (int kc = 0; kc < 12; ++kc) {
      short8 af = *(const short8*)&s_pb[lm][kc * 32 + q * 8];
      short8 bf = *(const short8*)&Brow[kc * 32 + q * 8];
      acc = __builtin_amdgcn_mfma_f32_16x16x32_bf16(af, bf, acc, 0, 0, 0);
    }
    if (q < 2) {                                    // D rows 0..7 only
#pragma unroll
      for (int r = 0; r < 4; ++r) {
        int i = i0 + q * 4 + r;
        int off = i * HF + h * 64 + f0 + lm;
        float o = acc[r];
        if (LAYER == 0) {
          float oe = (o > 0.f) ? o : (__expf(o) - 1.f);   // ELU
          float vv = resid_in[off] + oe;
          xcur_out[off] = vv;          // fp32 residual for layer 1
          x1b_out[off]  = f2bf(vv);    // bf16 operand for layer-1 GEMM
        } else {
          f_out[off] = resid_in[off] + o;   // final output, fp32
        }
      }
    }
  }
}

// ---------------------------------------------------------------------------
extern "C" void kernel_launch(void* const* d_in, const int* in_sizes, int n_in,
                              void* d_out, int out_size, void* d_ws, size_t ws_size,
                              hipStream_t stream) {
  const float* x   = (const float*)d_in[0];
  const int*   adj = (const int*)d_in[1];
  const float* Wl0 = (const float*)d_in[2];
  const float* Wr0 = (const float*)d_in[3];
  const float* a0  = (const float*)d_in[4];
  const float* Wl1 = (const float*)d_in[5];
  const float* Wr1 = (const float*)d_in[6];
  const float* a1  = (const float*)d_in[7];
  float* out = (float*)d_out;

  char* ws = (char*)d_ws;                       // ws is 256 MiB — spread out
  ushort_t* WT0  = (ushort_t*)(ws + 0L);        // 1 MB  [Wl0;Wr0]^T bf16
  ushort_t* WT1  = (ushort_t*)(ws + (1L << 20));    // 1 MB
  ushort_t* xb   = (ushort_t*)(ws + (2L << 20));    // 384 KB x bf16
  float*    G    = (float*)   (ws + (3L << 20));    // 1.5 MB (gr half used)
  ushort_t* grT  = (ushort_t*)(ws + (5L << 20));    // 384 KB gr^T bf16
  ushort_t* x1b  = (ushort_t*)(ws + (6L << 20));    // 384 KB
  ushort_t* glb  = (ushort_t*)(ws + (7L << 20));    // 384 KB gl bf16
  u64*      mbits= (u64*)     (ws + (8L << 20));    // 18 KB adjacency bits
  float*    xcur = (float*)   (ws + (9L << 20));    // 768 KB fp32 residual

  prep<<<dim3(16, 16, 6), 256, 0, stream>>>(x, adj, Wl0, Wr0, Wl1, Wr1,
                                            WT0, WT1, xb, mbits);
  gemm_mfma<<<dim3(24, 8), 256, 0, stream>>>(xb, WT0, G, glb, grT);
  attn_fused<0><<<dim3(48, 8), 384, 0, stream>>>(G, glb, grT, mbits, x, a0,
                                                 xcur, x1b, nullptr);
  gemm_mfma<<<dim3(24, 8), 256, 0, stream>>>(x1b, WT1, G, glb, grT);
  attn_fused<1><<<dim3(48, 8), 384, 0, stream>>>(G, glb, grT, mbits, xcur, a1,
                                                 nullptr, nullptr, out);
}